// Round 8
// baseline (550.648 us; speedup 1.0000x reference)
//
#include <hip/hip_runtime.h>
#include <hip/hip_bf16.h>

#define BN_EPS 1e-5f

using short8 = __attribute__((ext_vector_type(8))) short;
using f32x4  = __attribute__((ext_vector_type(4))) float;

#define FIX_SCALE 1048576.0f          // 2^20
#define FIX_MASK  ((1ULL << 42) - 1)
#define CNT_ONE   (1ULL << 42)
#define NPART 8

static __device__ __forceinline__ unsigned short f2bf(float f) {
  unsigned int u = __float_as_uint(f);
  unsigned int r = (u + 0x7fffu + ((u >> 16) & 1u)) >> 16;
  return (unsigned short)r;
}

// pack two fp32 -> bf16x2 word, round-half-up (1.5 ops/value; bias negligible)
static __device__ __forceinline__ unsigned int pkbf(float x, float y) {
  unsigned int a = (__float_as_uint(x) + 0x8000u) >> 16;
  unsigned int b = (__float_as_uint(y) + 0x8000u) & 0xffff0000u;
  return a | b;
}

// ------------------------------------------------- weight cast (bf16, n-major)

static __global__ void cast_weights(const float* __restrict__ W1, const float* __restrict__ Wres,
                                    const float* __restrict__ W2,
                                    unsigned short* __restrict__ BT1,
                                    unsigned short* __restrict__ BT2) {
  int i = blockIdx.x * blockDim.x + threadIdx.x;
  if (i < 256 * 256) {
    int n = i >> 8, k = i & 255;
    float v = (n < 128) ? W1[k * 128 + n] : Wres[k * 128 + (n - 128)];
    BT1[i] = f2bf(v);
  } else if (i < 256 * 256 + 128 * 128) {
    int j = i - 256 * 256;
    int n = j >> 7, k = j & 127;
    BT2[j] = f2bf(W2[k * 128 + n]);
  }
}

// ---------------------------------------------------------------- fused GEMM1 + hist
// No LDS, no barriers anywhere in this kernel.
// Blocks [0, gemmBlocks): GEMM1 C[M x 256] = A(fp32->bf16) @ BT1 (n-major).
//   MFMA fragments loaded DIRECTLY from global (A: 2x float4/lane, B: short8/lane);
//   K-loop fully unrolled -> compiler hoists loads, hides latency with ILP.
// Blocks [gemmBlocks, +histBlocks): XCD-partitioned degree histogram.
//   partition = blockIdx & 7 (round-robin block->XCD mapping heuristic) ->
//   atomics stay XCD-local. packedH[p][c]: cnt in [63:42], fixed ew-sum in [41:0].

static __global__ __launch_bounds__(256)
void fused_gemm1_hist(const float* __restrict__ A, const unsigned short* __restrict__ BT,
                      unsigned short* __restrict__ C0, float* __restrict__ C1, int M,
                      const int* __restrict__ col, const float* __restrict__ ew,
                      unsigned long long* __restrict__ packedH,
                      unsigned short* __restrict__ rank, int E, int gemmBlocks, int N) {
  if (blockIdx.x >= gemmBlocks) {
    // ---------------- hist half (atomic-pipe only)
    int e = (blockIdx.x - gemmBlocks) * blockDim.x + threadIdx.x;
    if (e < E) {
      int c = col[e];
      int part = blockIdx.x & (NPART - 1);
      unsigned long long fx = (unsigned long long)(unsigned int)(ew[e] * FIX_SCALE + 0.5f);
      unsigned long long old = atomicAdd(&packedH[(size_t)part * N + c], CNT_ONE | fx);
      rank[e] = (unsigned short)(old >> 42);
    }
    return;
  }

  // ---------------- gemm1 half (direct-fragment, barrier-free)
  int t = threadIdx.x;
  int wv = t >> 6, lane = t & 63;
  int quad = lane >> 4, l15 = lane & 15;
  int m0 = blockIdx.x * 64;
  int nbase = wv * 64;

  f32x4 acc[4][4];
#pragma unroll
  for (int i = 0; i < 4; ++i)
#pragma unroll
    for (int j = 0; j < 4; ++j) acc[i][j] = (f32x4){0.f, 0.f, 0.f, 0.f};

  // row pointers (clamped: pad-row outputs land in pad rows of C, never read)
  const float* Aptr[4];
#pragma unroll
  for (int mt = 0; mt < 4; ++mt) {
    int m = m0 + mt * 16 + l15;
    if (m >= M) m = M - 1;
    Aptr[mt] = A + (size_t)m * 256 + quad * 8;
  }
  const unsigned short* Bptr[4];
#pragma unroll
  for (int nt = 0; nt < 4; ++nt)
    Bptr[nt] = BT + (size_t)(nbase + nt * 16 + l15) * 256 + quad * 8;

#pragma unroll
  for (int kk = 0; kk < 8; ++kk) {     // k0 = kk*32
    short8 af[4], bf[4];
#pragma unroll
    for (int mt = 0; mt < 4; ++mt) {
      float4 a0 = *(const float4*)(Aptr[mt] + kk * 32);
      float4 a1 = *(const float4*)(Aptr[mt] + kk * 32 + 4);
      int4 pa;
      pa.x = (int)pkbf(a0.x, a0.y);
      pa.y = (int)pkbf(a0.z, a0.w);
      pa.z = (int)pkbf(a1.x, a1.y);
      pa.w = (int)pkbf(a1.z, a1.w);
      af[mt] = *(short8*)&pa;
    }
#pragma unroll
    for (int nt = 0; nt < 4; ++nt)
      bf[nt] = *(const short8*)(Bptr[nt] + kk * 32);
#pragma unroll
    for (int mt = 0; mt < 4; ++mt)
#pragma unroll
      for (int nt = 0; nt < 4; ++nt)
        acc[mt][nt] = __builtin_amdgcn_mfma_f32_16x16x32_bf16(af[mt], bf[nt], acc[mt][nt], 0, 0, 0);
  }

#pragma unroll
  for (int mt = 0; mt < 4; ++mt) {
#pragma unroll
    for (int nt = 0; nt < 4; ++nt) {
      int n = nbase + nt * 16 + l15;
#pragma unroll
      for (int reg = 0; reg < 4; ++reg) {
        size_t m = (size_t)(m0 + mt * 16 + quad * 4 + reg);
        if (nbase < 128) C0[m * 128 + n] = f2bf(acc[mt][nt][reg]);
        else             C1[m * 128 + (n - 128)] = acc[mt][nt][reg];
      }
    }
  }
}

// ---------------------------------------------------------------- scan
// scanA also folds partition-prefix (pofs) + unpack (dis, cnt).

#define SCAN_B 256
#define SCAN_I 4
static __global__ void scanA(const unsigned long long* __restrict__ packedH,
                             int* __restrict__ pofs,
                             float* __restrict__ dis, int* __restrict__ cnt,
                             int* __restrict__ start, int* __restrict__ blkSum, int N) {
  __shared__ int sh[SCAN_B];
  int t = threadIdx.x;
  int base = blockIdx.x * SCAN_B * SCAN_I + t * SCAN_I;
  int v[SCAN_I];
  int tot = 0;
#pragma unroll
  for (int j = 0; j < SCAN_I; ++j) {
    if (base + j < N) {
      int i = base + j;
      int cum = 0;
      unsigned long long fix = 0;
#pragma unroll
      for (int p = 0; p < NPART; ++p) {
        unsigned long long pv = packedH[(size_t)p * N + i];
        pofs[(size_t)p * N + i] = cum;
        cum += (int)(pv >> 42);
        fix += pv & FIX_MASK;
      }
      v[j] = cum;
      cnt[i] = cum;
      float deg = 1.0f + (float)fix * (1.0f / FIX_SCALE);
      dis[i] = rsqrtf(deg);
    } else v[j] = 0;
    tot += v[j];
  }
  sh[t] = tot;
  __syncthreads();
  int self = tot;
  for (int off = 1; off < SCAN_B; off <<= 1) {
    int add = (t >= off) ? sh[t - off] : 0;
    __syncthreads();
    sh[t] += add;
    __syncthreads();
  }
  int excl = sh[t] - self;
  if (t == SCAN_B - 1) blkSum[blockIdx.x] = sh[t];
  int run = excl;
#pragma unroll
  for (int j = 0; j < SCAN_I; ++j) {
    if (base + j < N) start[base + j] = run;
    run += v[j];
  }
}

static __global__ void scanB(const int* __restrict__ blkSum, int* __restrict__ blkOff, int nb) {
  __shared__ int sh[256];
  int t = threadIdx.x;
  int v = (t < nb) ? blkSum[t] : 0;
  sh[t] = v;
  __syncthreads();
  for (int off = 1; off < 256; off <<= 1) {
    int add = (t >= off) ? sh[t - off] : 0;
    __syncthreads();
    sh[t] += add;
    __syncthreads();
  }
  if (t < nb) blkOff[t] = sh[t] - v;
}

static __global__ void scanC(int* start, const int* __restrict__ blkOff, int N) {
  int i = blockIdx.x * blockDim.x + threadIdx.x;
  if (i < N) start[i] += blkOff[i / (SCAN_B * SCAN_I)];
}

// atomic-free placement: pos = start[col] + pofs[part][col] + rank.
// edges[pos] = (src, dis[src]*ew); dest dis folded into prop epilogue.
static __global__ void place_kernel(const int* __restrict__ row, const int* __restrict__ col,
                                    const float* __restrict__ ew, const float* __restrict__ dis,
                                    const int* __restrict__ start,
                                    const int* __restrict__ pofs,
                                    const unsigned short* __restrict__ rank,
                                    long long* __restrict__ edges, int E, int gB, int N) {
  int e = blockIdx.x * blockDim.x + threadIdx.x;
  if (e < E) {
    int r = row[e], c = col[e];
    int part = (gB + (e >> 8)) & (NPART - 1);
    int pos = start[c] + pofs[(size_t)part * N + c] + (int)rank[e];
    float nrm = dis[r] * ew[e];
    long long v = ((long long)__float_as_int(nrm) << 32) | (unsigned int)r;
    __builtin_nontemporal_store(v, &edges[pos]);
  }
}

// ---------------------------------------------------------------- GEMM2 (direct-fragment, barrier-free)
// C[Mp x 128] bf16 = A[Mp x 128] bf16 @ BT2[128 x 128] (n-major).
// 4 waves/block: wave -> (m-half, n-half) 64x64 of a 128x128 tile.

static __global__ __launch_bounds__(256)
void gemm2_mfma(const unsigned short* __restrict__ A, const unsigned short* __restrict__ BT,
                unsigned short* __restrict__ C) {
  int t = threadIdx.x;
  int wv = t >> 6, lane = t & 63;
  int quad = lane >> 4, l15 = lane & 15;
  int m0 = blockIdx.x * 128;
  int mb = (wv >> 1) * 64, nb = (wv & 1) * 64;

  f32x4 acc[4][4];
#pragma unroll
  for (int i = 0; i < 4; ++i)
#pragma unroll
    for (int j = 0; j < 4; ++j) acc[i][j] = (f32x4){0.f, 0.f, 0.f, 0.f};

  const unsigned short* Aptr[4];
  const unsigned short* Bptr[4];
#pragma unroll
  for (int mt = 0; mt < 4; ++mt)
    Aptr[mt] = A + (size_t)(m0 + mb + mt * 16 + l15) * 128 + quad * 8;
#pragma unroll
  for (int nt = 0; nt < 4; ++nt)
    Bptr[nt] = BT + (size_t)(nb + nt * 16 + l15) * 128 + quad * 8;

#pragma unroll
  for (int kk = 0; kk < 4; ++kk) {    // k0 = kk*32
    short8 af[4], bf[4];
#pragma unroll
    for (int mt = 0; mt < 4; ++mt) af[mt] = *(const short8*)(Aptr[mt] + kk * 32);
#pragma unroll
    for (int nt = 0; nt < 4; ++nt) bf[nt] = *(const short8*)(Bptr[nt] + kk * 32);
#pragma unroll
    for (int mt = 0; mt < 4; ++mt)
#pragma unroll
      for (int nt = 0; nt < 4; ++nt)
        acc[mt][nt] = __builtin_amdgcn_mfma_f32_16x16x32_bf16(af[mt], bf[nt], acc[mt][nt], 0, 0, 0);
  }

#pragma unroll
  for (int mt = 0; mt < 4; ++mt)
#pragma unroll
    for (int nt = 0; nt < 4; ++nt) {
      int n = nb + nt * 16 + l15;
#pragma unroll
      for (int reg = 0; reg < 4; ++reg) {
        size_t m = (size_t)(m0 + mb + mt * 16 + quad * 4 + reg);
        C[m * 128 + n] = f2bf(acc[mt][nt][reg]);
      }
    }
}

// ---------------------------------------------------------------- propagation core
// One wave per destination node; lane holds 2 channels (one bf16x2 word).
// Stored edge weight = dis[src]*ew; destination dis applied once at the end.

#define PROP_GATHER_BODY                                                        \
  int c0 = lane * 2;                                                            \
  float d = dis[w];                                                             \
  float acc0, acc1;                                                             \
  {                                                                             \
    unsigned int u = Hsrc[(size_t)w * 64 + lane];                               \
    acc0 = d * __uint_as_float(u << 16);                                        \
    acc1 = d * __uint_as_float(u & 0xffff0000u);                                \
  }                                                                             \
  int s = start[w], n = cnt[w];                                                 \
  int k = 0;                                                                    \
  while (k < n) {                                                               \
    int chunk = min(n - k, 64);                                                 \
    int idx = 0;                                                                \
    float wt = 0.f;                                                             \
    if (lane < chunk) {                                                         \
      long long ev = edges[s + k + lane];                                       \
      idx = (int)(unsigned int)(ev & 0xffffffffLL);                             \
      wt  = __int_as_float((int)(ev >> 32));                                    \
    }                                                                           \
    for (int j = 0; j < chunk; j += 8) {                                        \
      int   i0 = __shfl(idx, j + 0, 64), i1 = __shfl(idx, j + 1, 64);           \
      int   i2 = __shfl(idx, j + 2, 64), i3 = __shfl(idx, j + 3, 64);           \
      int   i4 = __shfl(idx, j + 4, 64), i5 = __shfl(idx, j + 5, 64);           \
      int   i6 = __shfl(idx, j + 6, 64), i7 = __shfl(idx, j + 7, 64);           \
      float w0 = __shfl(wt, j + 0, 64), w1 = __shfl(wt, j + 1, 64);             \
      float w2 = __shfl(wt, j + 2, 64), w3 = __shfl(wt, j + 3, 64);             \
      float w4 = __shfl(wt, j + 4, 64), w5 = __shfl(wt, j + 5, 64);             \
      float w6 = __shfl(wt, j + 6, 64), w7 = __shfl(wt, j + 7, 64);             \
      unsigned int u0 = Hsrc[(size_t)i0 * 64 + lane];                           \
      unsigned int u1 = Hsrc[(size_t)i1 * 64 + lane];                           \
      unsigned int u2 = Hsrc[(size_t)i2 * 64 + lane];                           \
      unsigned int u3 = Hsrc[(size_t)i3 * 64 + lane];                           \
      unsigned int u4 = Hsrc[(size_t)i4 * 64 + lane];                           \
      unsigned int u5 = Hsrc[(size_t)i5 * 64 + lane];                           \
      unsigned int u6 = Hsrc[(size_t)i6 * 64 + lane];                           \
      unsigned int u7 = Hsrc[(size_t)i7 * 64 + lane];                           \
      acc0 = fmaf(w0, __uint_as_float(u0 << 16), acc0);                         \
      acc1 = fmaf(w0, __uint_as_float(u0 & 0xffff0000u), acc1);                 \
      acc0 = fmaf(w1, __uint_as_float(u1 << 16), acc0);                         \
      acc1 = fmaf(w1, __uint_as_float(u1 & 0xffff0000u), acc1);                 \
      acc0 = fmaf(w2, __uint_as_float(u2 << 16), acc0);                         \
      acc1 = fmaf(w2, __uint_as_float(u2 & 0xffff0000u), acc1);                 \
      acc0 = fmaf(w3, __uint_as_float(u3 << 16), acc0);                         \
      acc1 = fmaf(w3, __uint_as_float(u3 & 0xffff0000u), acc1);                 \
      acc0 = fmaf(w4, __uint_as_float(u4 << 16), acc0);                         \
      acc1 = fmaf(w4, __uint_as_float(u4 & 0xffff0000u), acc1);                 \
      acc0 = fmaf(w5, __uint_as_float(u5 << 16), acc0);                         \
      acc1 = fmaf(w5, __uint_as_float(u5 & 0xffff0000u), acc1);                 \
      acc0 = fmaf(w6, __uint_as_float(u6 << 16), acc0);                         \
      acc1 = fmaf(w6, __uint_as_float(u6 & 0xffff0000u), acc1);                 \
      acc0 = fmaf(w7, __uint_as_float(u7 << 16), acc0);                         \
      acc1 = fmaf(w7, __uint_as_float(u7 & 0xffff0000u), acc1);                 \
    }                                                                           \
    k += chunk;                                                                 \
  }                                                                             \
  acc0 *= d;                                                                    \
  acc1 *= d;

// prop1: h1 = relu(bn1(agg + b1)) -> bf16 packed output
static __global__ __launch_bounds__(256)
void prop128_bf16out(const unsigned int* __restrict__ Hsrc,
                     const int* __restrict__ start, const int* __restrict__ cnt,
                     const long long* __restrict__ edges,
                     const float* __restrict__ dis,
                     const float* __restrict__ bvec,
                     const float* __restrict__ g, const float* __restrict__ be,
                     const float* __restrict__ mean, const float* __restrict__ var,
                     unsigned int* __restrict__ Outb, int N) {
  int w = (int)((blockIdx.x * blockDim.x + threadIdx.x) >> 6);
  int lane = threadIdx.x & 63;
  if (w >= N) return;
  PROP_GATHER_BODY
  float x0 = acc0 + bvec[c0];
  float x1 = acc1 + bvec[c0 + 1];
  float s0 = g[c0] * rsqrtf(var[c0] + BN_EPS);
  float s1 = g[c0 + 1] * rsqrtf(var[c0 + 1] + BN_EPS);
  x0 = fmaxf((x0 - mean[c0]) * s0 + be[c0], 0.f);
  x1 = fmaxf((x1 - mean[c0 + 1]) * s1 + be[c0 + 1], 0.f);
  unsigned int packed = (unsigned int)f2bf(x0) | ((unsigned int)f2bf(x1) << 16);
  Outb[(size_t)w * 64 + lane] = packed;
}

// prop2: h2 = relu(bn2(agg + b2 + res)); fused h3[w] = dot(h2_row, W3)
static __global__ __launch_bounds__(256)
void prop128_w3out(const unsigned int* __restrict__ Hsrc,
                   const int* __restrict__ start, const int* __restrict__ cnt,
                   const long long* __restrict__ edges,
                   const float* __restrict__ dis,
                   const float* __restrict__ bvec,
                   const float* __restrict__ g, const float* __restrict__ be,
                   const float* __restrict__ mean, const float* __restrict__ var,
                   const float* __restrict__ res, const float* __restrict__ W3,
                   float* __restrict__ h3, int N) {
  int w = (int)((blockIdx.x * blockDim.x + threadIdx.x) >> 6);
  int lane = threadIdx.x & 63;
  if (w >= N) return;
  PROP_GATHER_BODY
  float x0 = acc0 + bvec[c0] + res[(size_t)w * 128 + c0];
  float x1 = acc1 + bvec[c0 + 1] + res[(size_t)w * 128 + c0 + 1];
  float s0 = g[c0] * rsqrtf(var[c0] + BN_EPS);
  float s1 = g[c0 + 1] * rsqrtf(var[c0 + 1] + BN_EPS);
  x0 = fmaxf((x0 - mean[c0]) * s0 + be[c0], 0.f);
  x1 = fmaxf((x1 - mean[c0 + 1]) * s1 + be[c0 + 1], 0.f);
  float v = x0 * W3[c0] + x1 * W3[c0 + 1];
#pragma unroll
  for (int off = 32; off > 0; off >>= 1) v += __shfl_down(v, off, 64);
  if (lane == 0) h3[w] = v;
}

// ---------------------------------------------------------------- final 1-wide propagation

static __global__ void prop3_kernel(const float* __restrict__ h3,
                                    const int* __restrict__ start, const int* __restrict__ cnt,
                                    const long long* __restrict__ edges,
                                    const float* __restrict__ dis, const float* __restrict__ b3,
                                    float* __restrict__ out, int N) {
  int i = blockIdx.x * blockDim.x + threadIdx.x;
  if (i >= N) return;
  float d = dis[i];
  float acc = d * h3[i];
  int s = start[i], n = cnt[i];
  for (int k = 0; k < n; ++k) {
    long long ev = edges[s + k];
    int src = (int)(unsigned int)(ev & 0xffffffffLL);
    float wt = __int_as_float((int)(ev >> 32));
    acc = fmaf(wt, h3[src], acc);
  }
  out[i] = acc * d + b3[0];
}

// ---------------------------------------------------------------- launch

extern "C" void kernel_launch(void* const* d_in, const int* in_sizes, int n_in,
                              void* d_out, int out_size, void* d_ws, size_t ws_size,
                              hipStream_t stream) {
  const float* x    = (const float*)d_in[0];
  const int*   ei   = (const int*)d_in[1];
  const float* ew   = (const float*)d_in[2];
  const float* W1   = (const float*)d_in[3];
  const float* b1   = (const float*)d_in[4];
  const float* W2   = (const float*)d_in[5];
  const float* b2   = (const float*)d_in[6];
  const float* W3   = (const float*)d_in[7];
  const float* b3   = (const float*)d_in[8];
  const float* Wres = (const float*)d_in[9];
  const float* g1   = (const float*)d_in[10];
  const float* be1  = (const float*)d_in[11];
  const float* m1   = (const float*)d_in[12];
  const float* v1   = (const float*)d_in[13];
  const float* g2   = (const float*)d_in[14];
  const float* be2  = (const float*)d_in[15];
  const float* m2   = (const float*)d_in[16];
  const float* v2   = (const float*)d_in[17];

  int Hh = in_sizes[4];            // 128
  int V  = in_sizes[3] / Hh;       // 256
  int N  = in_sizes[0] / V;        // 100000
  int E  = in_sizes[2];            // 1600000
  const int* row = ei;
  const int* col = ei + E;

  int Mp = ((N + 127) / 128) * 128;

  char* p = (char*)d_ws;
  auto alloc = [&](size_t bytes) -> char* {
    char* r = p;
    p += (bytes + 255) & ~(size_t)255;
    return r;
  };
  unsigned long long* packedH = (unsigned long long*)alloc((size_t)NPART * N * 8);
  int*   pofs   = (int*)  alloc((size_t)NPART * N * 4);
  float* dis    = (float*)alloc((size_t)N * 4);
  int*   cnt    = (int*)  alloc((size_t)N * 4);
  int*   startA = (int*)  alloc((size_t)N * 4);
  int*   blkSum = (int*)  alloc(256 * 4);
  int*   blkOff = (int*)  alloc(256 * 4);
  unsigned short* rank = (unsigned short*)alloc((size_t)E * 2);
  long long* edges = (long long*)alloc((size_t)E * 8);
  float* h3     = (float*)alloc((size_t)N * 4);
  unsigned short* BT1 = (unsigned short*)alloc((size_t)256 * 256 * 2);
  unsigned short* BT2 = (unsigned short*)alloc((size_t)128 * 128 * 2);
  unsigned short* bufG  = (unsigned short*)alloc((size_t)Mp * 128 * 2);  // h0, then h1W2 (bf16)
  unsigned short* bufH1 = (unsigned short*)alloc((size_t)Mp * 128 * 2);  // h1 bf16
  float* bufRes = (float*)alloc((size_t)Mp * 128 * 4);                   // x@Wres fp32
  (void)ws_size; (void)n_in; (void)out_size;

  int TB = 256;
  hipMemsetAsync(packedH, 0, (size_t)NPART * N * 8, stream);
  cast_weights<<<(256 * 256 + 128 * 128 + TB - 1) / TB, TB, 0, stream>>>(W1, Wres, W2, BT1, BT2);

  // fused: GEMM1 (blocks [0,gB)) + hist (blocks [gB, gB+hB))
  int gB = Mp / 64;
  int hB = (E + TB - 1) / TB;
  fused_gemm1_hist<<<gB + hB, TB, 0, stream>>>(x, BT1, bufG, bufRes, N,
                                               col, ew, packedH, rank, E, gB, N);

  int nb = (N + SCAN_B * SCAN_I - 1) / (SCAN_B * SCAN_I);
  scanA<<<nb, SCAN_B, 0, stream>>>(packedH, pofs, dis, cnt, startA, blkSum, N);
  scanB<<<1, 256, 0, stream>>>(blkSum, blkOff, nb);
  scanC<<<(N + TB - 1) / TB, TB, 0, stream>>>(startA, blkOff, N);
  place_kernel<<<(E + TB - 1) / TB, TB, 0, stream>>>(row, col, ew, dis, startA, pofs,
                                                     rank, edges, E, gB, N);

  // prop1: h1 = relu(bn1(agg(h0) + b1)) -> bufH1 (bf16)
  int propBlocks = (int)(((size_t)N * 64 + TB - 1) / TB);
  prop128_bf16out<<<propBlocks, TB, 0, stream>>>((const unsigned int*)bufG, startA, cnt,
                                                 edges, dis, b1, g1, be1, m1, v1,
                                                 (unsigned int*)bufH1, N);

  // GEMM2: h1 @ W2 -> bufG (bf16, reused)
  gemm2_mfma<<<Mp / 128, 256, 0, stream>>>(bufH1, BT2, bufG);

  // prop2 + fused W3: h3 = relu(bn2(agg(h1W2) + b2 + res)) . W3
  prop128_w3out<<<propBlocks, TB, 0, stream>>>((const unsigned int*)bufG, startA, cnt,
                                               edges, dis, b2, g2, be2, m2, v2,
                                               bufRes, W3, h3, N);

  // out = agg(h3) + b3
  prop3_kernel<<<(N + TB - 1) / TB, TB, 0, stream>>>(h3, startA, cnt, edges,
                                                     dis, b3, (float*)d_out, N);
}